// Round 3
// baseline (10209.091 us; speedup 1.0000x reference)
//
#include <hip/hip_runtime.h>
#include <math.h>

typedef __bf16 bf16_t;
typedef __bf16 bf16x8 __attribute__((ext_vector_type(8)));
typedef float f32x4 __attribute__((ext_vector_type(4)));

// ---------------------------------------------------------------------------
// GEMM v3: C[M,N](fp32) = A[M,K](bf16) @ W[N,K](bf16)^T + bias
// Block: 256 thr / 4 waves, tile 64m x 64n, BK=128 macro-tiles.
// Each wave computes the FULL 64x64 tile over its 32-deep k-slice
// (4 A-frags x 4 B-frags = 16 MFMA per macro-iter, 0.5KB LDS read/MFMA),
// then partials are reduced across waves via LDS (2 rounds of 32KB).
// EPI 0: C = acc + bias (fp32).
// EPI 1: fused GRU combine (gate n-tiles j=0..3 = r,z,i_n,h_n of channel
//        cch=(bn>>2)+col; weights pre-reordered by build_w4). Updates hf
//        in place, writes bf16 h to d1/d2. Also XCD-swizzles blockIdx.
// ---------------------------------------------------------------------------
template<int EPI>
__global__ __launch_bounds__(256, 1) void gemm_v3(
    const bf16_t* __restrict__ A, const bf16_t* __restrict__ W,
    const float* __restrict__ bias, int K,
    float* __restrict__ C, int ldc,
    float* __restrict__ hf,
    bf16_t* __restrict__ d1, int ld1, int off1,
    bf16_t* __restrict__ d2, int ld2, int off2)
{
    // staging: A-tile [64][136], B-tile [64][136] bf16 = 34816 B.
    // Reused after the K-loop as the 32KB fp32 reduction buffer.
    __shared__ __align__(16) bf16_t lds[2 * 64 * 136];
    bf16_t* ldsA = lds;
    bf16_t* ldsB = lds + 64 * 136;

    int bx = blockIdx.x, by = blockIdx.y;
    if (EPI == 1) {                     // grid (64,4): XCD-aware remap
        int d = by * 64 + bx;
        bx = (d & 7) * 8 + ((d >> 3) & 7);
        by = d >> 6;
    }
    const int bm = by * 64, bn = bx * 64;
    const int tid = threadIdx.x;
    const int lane = tid & 63, wv = tid >> 6;
    const int quad = lane >> 4, col = lane & 15;

    // staging map: thread t -> row t>>2, k-chunks (t&3)*8 + {0,32,64,96}
    const int srow = tid >> 2;
    const int sk = (tid & 3) * 8;
    const bf16_t* gA = A + (size_t)(bm + srow) * K + sk;
    const bf16_t* gW = W + (size_t)(bn + srow) * K + sk;
    const unsigned swoff = srow * 136 + sk;

    // frag read base: wave wv owns k-slice [wv*32, wv*32+32)
    const unsigned fr = col * 136 + wv * 32 + quad * 8;

    f32x4 acc[4][4];
#pragma unroll
    for (int i = 0; i < 4; i++)
#pragma unroll
        for (int j = 0; j < 4; j++)
#pragma unroll
            for (int e = 0; e < 4; e++) acc[i][j][e] = 0.f;

    int4 pa[4], pb[4];
#pragma unroll
    for (int c4 = 0; c4 < 4; c4++) {
        pa[c4] = *(const int4*)(gA + c4 * 32);
        pb[c4] = *(const int4*)(gW + c4 * 32);
    }
    gA += 128; gW += 128;

    const int nit = K >> 7;
    for (int it = 0; it < nit; ++it) {
        __syncthreads();
#pragma unroll
        for (int c4 = 0; c4 < 4; c4++) {
            *(int4*)(ldsA + swoff + c4 * 32) = pa[c4];
            *(int4*)(ldsB + swoff + c4 * 32) = pb[c4];
        }
        __syncthreads();
        if (it + 1 < nit) {
#pragma unroll
            for (int c4 = 0; c4 < 4; c4++) {
                pa[c4] = *(const int4*)(gA + c4 * 32);
                pb[c4] = *(const int4*)(gW + c4 * 32);
            }
            gA += 128; gW += 128;
        }
        bf16x8 af[4], bfr[4];
#pragma unroll
        for (int i = 0; i < 4; i++) af[i]  = *(const bf16x8*)(ldsA + fr + i * 16 * 136);
#pragma unroll
        for (int j = 0; j < 4; j++) bfr[j] = *(const bf16x8*)(ldsB + fr + j * 16 * 136);
#pragma unroll
        for (int i = 0; i < 4; i++)
#pragma unroll
            for (int j = 0; j < 4; j++)
                acc[i][j] = __builtin_amdgcn_mfma_f32_16x16x32_bf16(af[i], bfr[j], acc[i][j], 0, 0, 0);
    }

    // ---- cross-wave k-reduction (2 rounds of 2 m-tiles each) ----
    // red layout (f32x4 units): [w][ip][quad][j][col] ; vec elems = rows r0..3
    f32x4* red = (f32x4*)lds;
    f32x4 cacc[4];
#pragma unroll
    for (int h = 0; h < 2; ++h) {
        __syncthreads();
#pragma unroll
        for (int ip = 0; ip < 2; ip++)
#pragma unroll
            for (int j = 0; j < 4; j++)
                red[(((wv * 2 + ip) * 4 + quad) * 4 + j) * 16 + col] = acc[2 * h + ip][j];
        __syncthreads();
        if ((wv >> 1) == h) {
            const int ip = wv & 1;
#pragma unroll
            for (int j = 0; j < 4; j++) {
                f32x4 s = red[((ip * 4 + quad) * 4 + j) * 16 + col];
#pragma unroll
                for (int ws = 1; ws < 4; ws++)
                    s += red[(((ws * 2 + ip) * 4 + quad) * 4 + j) * 16 + col];
                cacc[j] = s;
            }
        }
    }

    // ---- epilogue: wave wv owns rows bm + wv*16 + quad*4 + r ----
    if (EPI == 0) {
#pragma unroll
        for (int j = 0; j < 4; j++) {
            const int n = bn + j * 16 + col;
            const float bj = bias[n];
#pragma unroll
            for (int r = 0; r < 4; r++) {
                const int m = bm + wv * 16 + quad * 4 + r;
                C[(size_t)m * ldc + n] = cacc[j][r] + bj;
            }
        }
    } else {
        const int cch = (bn >> 2) + col;
        const float br  = bias[bn + col];
        const float bz  = bias[bn + 16 + col];
        const float bin = bias[bn + 32 + col];
        const float bhn = bias[bn + 48 + col];
#pragma unroll
        for (int r = 0; r < 4; r++) {
            const int m = bm + wv * 16 + quad * 4 + r;
            const float gr  = cacc[0][r] + br;
            const float gz  = cacc[1][r] + bz;
            const float gin = cacc[2][r] + bin;
            const float ghn = cacc[3][r] + bhn;
            const float rr = 1.f / (1.f + __expf(-gr));
            const float zz = 1.f / (1.f + __expf(-gz));
            const float nn = tanhf(gin + rr * ghn);
            const size_t hidx = (size_t)m * 1024 + cch;
            const float hnew = (1.f - zz) * nn + zz * hf[hidx];
            hf[hidx] = hnew;
            const bf16_t hb = (bf16_t)hnew;
            d1[(size_t)m * ld1 + off1 + cch] = hb;
            d2[(size_t)m * ld2 + off2 + cch] = hb;
        }
    }
}

// ---------------------------------------------------------------------------
// Build fused GRU weight matrix W4[4096, K] (K = Kx + 1024), bf16, row order
// n' = (c>>4)*64 + g*16 + (c&15); g: 0=r, 1=z, 2=i_n (x only), 3=h_n (h only).
// ---------------------------------------------------------------------------
__global__ __launch_bounds__(256) void build_w4(
    const float* __restrict__ Wih, const float* __restrict__ Whh,
    const float* __restrict__ bih, const float* __restrict__ bhh,
    bf16_t* __restrict__ W4, float* __restrict__ b4, int Kx)
{
    const int K = Kx + 1024;
    const int tpr = K >> 2;
    const int idx = blockIdx.x * 256 + threadIdx.x;
    const int np = idx / tpr;
    const int k4 = (idx - np * tpr) * 4;
    const int c = ((np >> 6) << 4) + (np & 15);
    const int g = (np >> 4) & 3;
    const int srow = (g == 0 ? c : (g == 1 ? 1024 + c : 2048 + c));
    float4 v = make_float4(0.f, 0.f, 0.f, 0.f);
    if (k4 < Kx) {
        if (g != 3) v = *(const float4*)(Wih + (size_t)srow * Kx + k4);
    } else {
        if (g != 2) v = *(const float4*)(Whh + (size_t)srow * 1024 + (k4 - Kx));
    }
    bf16_t* dst = W4 + (size_t)np * K + k4;
    dst[0] = (bf16_t)v.x; dst[1] = (bf16_t)v.y;
    dst[2] = (bf16_t)v.z; dst[3] = (bf16_t)v.w;
    if (k4 == 0) {
        b4[np] = (g == 0) ? bih[c] + bhh[c]
               : (g == 1) ? bih[1024 + c] + bhh[1024 + c]
               : (g == 2) ? bih[2048 + c] : bhh[2048 + c];
    }
}

__global__ __launch_bounds__(256) void conv_bf16(
    const float* __restrict__ src, bf16_t* __restrict__ dst)
{
    const int i4 = (blockIdx.x * 256 + threadIdx.x) * 4;
    float4 v = *(const float4*)(src + i4);
    dst[i4 + 0] = (bf16_t)v.x; dst[i4 + 1] = (bf16_t)v.y;
    dst[i4 + 2] = (bf16_t)v.z; dst[i4 + 3] = (bf16_t)v.w;
}

__global__ __launch_bounds__(256) void init_state(
    const float* __restrict__ hidden, float* __restrict__ h0f,
    float* __restrict__ h1f, bf16_t* __restrict__ A0_0, bf16_t* __restrict__ A1_0)
{
    const int i = blockIdx.x * 256 + threadIdx.x;   // over 262144
    const int m = i >> 10, c = i & 1023;
    const float h0 = hidden[i], h1 = hidden[262144 + i];
    h0f[i] = h0; h1f[i] = h1;
    A0_0[(size_t)m * 1280 + 256 + c] = (bf16_t)h0;
    A1_0[(size_t)m * 2048 + 1024 + c] = (bf16_t)h1;
    if (c < 256) A0_0[(size_t)m * 1280 + c] = (bf16_t)0.f;
}

// ---------------------------------------------------------------------------
// LayerNorm (biased var, eps=1e-5) + exact GELU, bf16 out. One row per block.
// ---------------------------------------------------------------------------
__device__ __forceinline__ float block_reduce_sum(float v, float* red)
{
#pragma unroll
    for (int o = 32; o > 0; o >>= 1) v += __shfl_xor(v, o, 64);
    const int wid = threadIdx.x >> 6;
    if ((threadIdx.x & 63) == 0) red[wid] = v;
    __syncthreads();
    float s = red[0] + red[1] + red[2] + red[3];
    __syncthreads();
    return s;
}

template <int N>
__global__ __launch_bounds__(256) void ln_gelu(
    const float* __restrict__ X, const float* __restrict__ g,
    const float* __restrict__ b, bf16_t* __restrict__ Y)
{
    __shared__ float red[4];
    const int row = blockIdx.x;
    const int tid = threadIdx.x;
    constexpr int PT = N / 256;
    float v[PT];
    float s = 0.f;
#pragma unroll
    for (int i = 0; i < PT; i++) {
        v[i] = X[(size_t)row * N + tid + i * 256];
        s += v[i];
    }
    const float mu = block_reduce_sum(s, red) * (1.f / N);
    float s2 = 0.f;
#pragma unroll
    for (int i = 0; i < PT; i++) { float d = v[i] - mu; s2 += d * d; }
    const float var = block_reduce_sum(s2, red) * (1.f / N);
    const float inv = rsqrtf(var + 1e-5f);
#pragma unroll
    for (int i = 0; i < PT; i++) {
        const int c = tid + i * 256;
        const float t = (v[i] - mu) * inv * g[c] + b[c];
        Y[(size_t)row * N + c] = (bf16_t)(0.5f * t * (1.f + erff(t * 0.70710678118654752f)));
    }
}

// ---------------------------------------------------------------------------
// fc3 (K=512, N=256, bf16) + softmax, fused. Block = 4 rows (1 wave/row).
// Lane l owns cols {l, l+64, l+128, l+192}. Writes dout[b,t,:] + bf16 feedback.
// ---------------------------------------------------------------------------
__global__ __launch_bounds__(256) void fc3_softmax(
    const bf16_t* __restrict__ A, const bf16_t* __restrict__ W,
    const float* __restrict__ bias, float* __restrict__ dout,
    bf16_t* __restrict__ a0w, int t)
{
    const int wv = threadIdx.x >> 6, lane = threadIdx.x & 63;
    const int row = blockIdx.x * 4 + wv;
    const bf16_t* a = A + (size_t)row * 512;
    float acc[4];
#pragma unroll
    for (int j = 0; j < 4; j++) acc[j] = bias[lane + 64 * j];
    for (int k = 0; k < 512; k += 8) {
        bf16x8 a8 = *(const bf16x8*)(a + k);        // wave-uniform broadcast
#pragma unroll
        for (int j = 0; j < 4; j++) {
            bf16x8 w8 = *(const bf16x8*)(W + (size_t)(lane + 64 * j) * 512 + k);
            float s = 0.f;
#pragma unroll
            for (int e = 0; e < 8; e++) s += (float)a8[e] * (float)w8[e];
            acc[j] += s;
        }
    }
    float mx = fmaxf(fmaxf(acc[0], acc[1]), fmaxf(acc[2], acc[3]));
#pragma unroll
    for (int o = 32; o > 0; o >>= 1) mx = fmaxf(mx, __shfl_xor(mx, o, 64));
    float e[4], s = 0.f;
#pragma unroll
    for (int j = 0; j < 4; j++) { e[j] = expf(acc[j] - mx); s += e[j]; }
#pragma unroll
    for (int o = 32; o > 0; o >>= 1) s += __shfl_xor(s, o, 64);
    const float inv = 1.f / s;
#pragma unroll
    for (int j = 0; j < 4; j++) {
        const float p = e[j] * inv;
        const int c = lane + 64 * j;
        dout[((size_t)row * 64 + t) * 256 + c] = p;
        a0w[(size_t)row * 1280 + c] = (bf16_t)p;
    }
}

extern "C" void kernel_launch(void* const* d_in, const int* in_sizes, int n_in,
                              void* d_out, int out_size, void* d_ws, size_t ws_size,
                              hipStream_t stream)
{
    const float* hidden = (const float*)d_in[0];
    const float* W_ih0  = (const float*)d_in[1];
    const float* W_hh0  = (const float*)d_in[2];
    const float* b_ih0  = (const float*)d_in[3];
    const float* b_hh0  = (const float*)d_in[4];
    const float* W_ih1  = (const float*)d_in[5];
    const float* W_hh1  = (const float*)d_in[6];
    const float* b_ih1  = (const float*)d_in[7];
    const float* b_hh1  = (const float*)d_in[8];
    const float* fc1_w  = (const float*)d_in[9];
    const float* fc1_b  = (const float*)d_in[10];
    const float* ln1_g  = (const float*)d_in[11];
    const float* ln1_b  = (const float*)d_in[12];
    const float* fc2_w  = (const float*)d_in[13];
    const float* fc2_b  = (const float*)d_in[14];
    const float* ln2_g  = (const float*)d_in[15];
    const float* ln2_b  = (const float*)d_in[16];
    const float* fc3_w  = (const float*)d_in[17];
    const float* fc3_b  = (const float*)d_in[18];
    float* dout = (float*)d_out;

    char* p = (char*)d_ws;
    auto alloc = [&](size_t bytes) { void* r = (void*)p; p += (bytes + 255) & ~(size_t)255; return r; };
    float*  h0f   = (float*)alloc(262144 * 4);
    float*  h1f   = (float*)alloc(262144 * 4);
    bf16_t* A0[2] = { (bf16_t*)alloc(256 * 1280 * 2), (bf16_t*)alloc(256 * 1280 * 2) };
    bf16_t* A1[2] = { (bf16_t*)alloc(256 * 2048 * 2), (bf16_t*)alloc(256 * 2048 * 2) };
    bf16_t* h1b   = (bf16_t*)alloc(262144 * 2);
    float*  a1r   = (float*)alloc(262144 * 4);
    bf16_t* a1b   = (bf16_t*)alloc(262144 * 2);
    float*  a2r   = (float*)alloc(131072 * 4);
    bf16_t* a2b   = (bf16_t*)alloc(131072 * 2);
    float*  b4_0  = (float*)alloc(4096 * 4);
    float*  b4_1  = (float*)alloc(4096 * 4);
    bf16_t* W4_0  = (bf16_t*)alloc((size_t)4096 * 1280 * 2);
    bf16_t* W4_1  = (bf16_t*)alloc((size_t)4096 * 2048 * 2);
    bf16_t* fc1wb = (bf16_t*)alloc((size_t)1048576 * 2);
    bf16_t* fc2wb = (bf16_t*)alloc((size_t)524288 * 2);
    bf16_t* fc3wb = (bf16_t*)alloc((size_t)131072 * 2);

    // weight prep (graph-safe, every call)
    build_w4<<<5120, 256, 0, stream>>>(W_ih0, W_hh0, b_ih0, b_hh0, W4_0, b4_0, 256);
    build_w4<<<8192, 256, 0, stream>>>(W_ih1, W_hh1, b_ih1, b_hh1, W4_1, b4_1, 1024);
    conv_bf16<<<1024, 256, 0, stream>>>(fc1_w, fc1wb);
    conv_bf16<<<512, 256, 0, stream>>>(fc2_w, fc2wb);
    conv_bf16<<<128, 256, 0, stream>>>(fc3_w, fc3wb);
    init_state<<<1024, 256, 0, stream>>>(hidden, h0f, h1f, A0[0], A1[0]);

    for (int t = 0; t < 64; t++) {
        bf16_t* A0r = A0[t & 1];
        bf16_t* A0w = A0[(t + 1) & 1];
        bf16_t* A1r = A1[t & 1];
        bf16_t* A1w = A1[(t + 1) & 1];

        // GRU layer 0: reads A0r=[out|h0]; updates h0f; writes bf16 h0 into
        // A1r[:, :1024] (gru1, this step) and A0w[:, 256:1280] (next step).
        gemm_v3<1><<<dim3(64, 4), 256, 0, stream>>>(
            A0r, W4_0, b4_0, 1280, nullptr, 0,
            h0f, A1r, 2048, 0, A0w, 1280, 256);
        // GRU layer 1: reads A1r=[h0_new|h1_old]; updates h1f; writes bf16 h1
        // into A1w[:, 1024:] (next step) and h1b (fc1 input).
        gemm_v3<1><<<dim3(64, 4), 256, 0, stream>>>(
            A1r, W4_1, b4_1, 2048, nullptr, 0,
            h1f, A1w, 2048, 1024, h1b, 1024, 0);
        // FC head
        gemm_v3<0><<<dim3(16, 4), 256, 0, stream>>>(
            h1b, fc1wb, fc1_b, 1024, a1r, 1024, nullptr, nullptr, 0, 0, nullptr, 0, 0);
        ln_gelu<1024><<<256, 256, 0, stream>>>(a1r, ln1_g, ln1_b, a1b);
        gemm_v3<0><<<dim3(8, 4), 256, 0, stream>>>(
            a1b, fc2wb, fc2_b, 1024, a2r, 512, nullptr, nullptr, 0, 0, nullptr, 0, 0);
        ln_gelu<512><<<256, 256, 0, stream>>>(a2r, ln2_g, ln2_b, a2b);
        fc3_softmax<<<64, 256, 0, stream>>>(a2b, fc3wb, fc3_b, dout, A0w, t);
    }
}

// Round 4
// 6872.574 us; speedup vs baseline: 1.4855x; 1.4855x over previous
//
#include <hip/hip_runtime.h>
#include <math.h>

typedef __bf16 bf16_t;
typedef __bf16 bf16x8 __attribute__((ext_vector_type(8)));
typedef float f32x4 __attribute__((ext_vector_type(4)));

// ---------------------------------------------------------------------------
// GEMM v4: C[M,N](fp32) = A[M,K](bf16) @ W[N,K](bf16)^T + bias
// Block: 128 thr / 2 waves, tile 32m x 64n. Wave w owns rows [w*16, w*16+16).
// Double-buffered LDS staging (BK=32), ONE barrier per K-iter.
// EPI 0: C = acc + bias (fp32).
// EPI 1: fused GRU combine (n-tiles j=0..3 = gates r,z,i_n,h_n of channel
//        cch=(bn>>2)+col; weights pre-reordered by build_w4). Updates hf in
//        place, writes bf16 h to d1/d2. XCD-swizzles block ids so each XCD's
//        L2 keeps an 8-n-block weight slice (<=2MB) resident.
// ---------------------------------------------------------------------------
template<int EPI>
__global__ __launch_bounds__(128) void gemm_v4(
    const bf16_t* __restrict__ A, const bf16_t* __restrict__ W,
    const float* __restrict__ bias, int K,
    float* __restrict__ C, int ldc,
    float* __restrict__ hf,
    bf16_t* __restrict__ d1, int ld1, int off1,
    bf16_t* __restrict__ d2, int ld2, int off2)
{
    __shared__ __align__(16) bf16_t ldsA[2][32 * 40];
    __shared__ __align__(16) bf16_t ldsB[2][64 * 40];

    int bx = blockIdx.x, by = blockIdx.y;
    if (EPI == 1) {                     // grid (64,8): XCD-aware remap
        int d = by * 64 + bx;
        bx = (d & 7) * 8 + ((d >> 3) & 7);   // n-block: XCD x -> [8x, 8x+8)
        by = d >> 6;                          // m-block 0..7
    }
    const int bm = by * 32, bn = bx * 64;
    const int tid = threadIdx.x;
    const int lane = tid & 63, wv = tid >> 6;
    const int quad = lane >> 4, col = lane & 15;

    // staging map: thread t -> row t>>2 (0..31), k-chunk (t&3)*8
    const int srow = tid >> 2;
    const int sk = (tid & 3) * 8;
    const bf16_t* gA  = A + (size_t)(bm + srow) * K + sk;
    const bf16_t* gW0 = W + (size_t)(bn + srow) * K + sk;
    const bf16_t* gW1 = W + (size_t)(bn + srow + 32) * K + sk;
    const unsigned swA  = srow * 40 + sk;
    const unsigned swB0 = srow * 40 + sk;
    const unsigned swB1 = (srow + 32) * 40 + sk;

    const unsigned frA = (wv * 16 + col) * 40 + quad * 8;
    const unsigned frB = col * 40 + quad * 8;

    f32x4 acc[4];
#pragma unroll
    for (int j = 0; j < 4; j++)
#pragma unroll
        for (int e = 0; e < 4; e++) acc[j][e] = 0.f;

    // prologue: load + write buffer 0
    int4 pa  = *(const int4*)gA;
    int4 pb0 = *(const int4*)gW0;
    int4 pb1 = *(const int4*)gW1;
    gA += 32; gW0 += 32; gW1 += 32;
    *(int4*)(ldsA[0] + swA)  = pa;
    *(int4*)(ldsB[0] + swB0) = pb0;
    *(int4*)(ldsB[0] + swB1) = pb1;
    __syncthreads();

    const int nit = K >> 5;
    for (int it = 0; it < nit; ++it) {
        const bf16_t* bufA = ldsA[it & 1];
        const bf16_t* bufB = ldsB[it & 1];
        if (it + 1 < nit) {                  // prefetch next macro-tile
            pa  = *(const int4*)gA;
            pb0 = *(const int4*)gW0;
            pb1 = *(const int4*)gW1;
            gA += 32; gW0 += 32; gW1 += 32;
        }
        bf16x8 af = *(const bf16x8*)(bufA + frA);
        bf16x8 b0 = *(const bf16x8*)(bufB + frB);
        bf16x8 b1 = *(const bf16x8*)(bufB + frB + 16 * 40);
        bf16x8 b2 = *(const bf16x8*)(bufB + frB + 32 * 40);
        bf16x8 b3 = *(const bf16x8*)(bufB + frB + 48 * 40);
        acc[0] = __builtin_amdgcn_mfma_f32_16x16x32_bf16(af, b0, acc[0], 0, 0, 0);
        acc[1] = __builtin_amdgcn_mfma_f32_16x16x32_bf16(af, b1, acc[1], 0, 0, 0);
        acc[2] = __builtin_amdgcn_mfma_f32_16x16x32_bf16(af, b2, acc[2], 0, 0, 0);
        acc[3] = __builtin_amdgcn_mfma_f32_16x16x32_bf16(af, b3, acc[3], 0, 0, 0);
        if (it + 1 < nit) {                  // write other buffer
            bf16_t* nA = ldsA[(it + 1) & 1];
            bf16_t* nB = ldsB[(it + 1) & 1];
            *(int4*)(nA + swA)  = pa;
            *(int4*)(nB + swB0) = pb0;
            *(int4*)(nB + swB1) = pb1;
        }
        __syncthreads();
    }

    // epilogue: wave wv owns rows bm + wv*16 + quad*4 + r
    if (EPI == 0) {
#pragma unroll
        for (int j = 0; j < 4; j++) {
            const int n = bn + j * 16 + col;
            const float bj = bias[n];
#pragma unroll
            for (int r = 0; r < 4; r++) {
                const int m = bm + wv * 16 + quad * 4 + r;
                C[(size_t)m * ldc + n] = acc[j][r] + bj;
            }
        }
    } else {
        const int cch = (bn >> 2) + col;
        const float br  = bias[bn + col];
        const float bz  = bias[bn + 16 + col];
        const float bin = bias[bn + 32 + col];
        const float bhn = bias[bn + 48 + col];
#pragma unroll
        for (int r = 0; r < 4; r++) {
            const int m = bm + wv * 16 + quad * 4 + r;
            const float gr  = acc[0][r] + br;
            const float gz  = acc[1][r] + bz;
            const float gin = acc[2][r] + bin;
            const float ghn = acc[3][r] + bhn;
            const float rr = 1.f / (1.f + __expf(-gr));
            const float zz = 1.f / (1.f + __expf(-gz));
            const float nn = tanhf(gin + rr * ghn);
            const size_t hidx = (size_t)m * 1024 + cch;
            const float hnew = (1.f - zz) * nn + zz * hf[hidx];
            hf[hidx] = hnew;
            const bf16_t hb = (bf16_t)hnew;
            d1[(size_t)m * ld1 + off1 + cch] = hb;
            d2[(size_t)m * ld2 + off2 + cch] = hb;
        }
    }
}

// ---------------------------------------------------------------------------
// Build fused GRU weight matrix W4[4096, K] (K = Kx + 1024), bf16, row order
// n' = (c>>4)*64 + g*16 + (c&15); g: 0=r, 1=z, 2=i_n (x only), 3=h_n (h only).
// ---------------------------------------------------------------------------
__global__ __launch_bounds__(256) void build_w4(
    const float* __restrict__ Wih, const float* __restrict__ Whh,
    const float* __restrict__ bih, const float* __restrict__ bhh,
    bf16_t* __restrict__ W4, float* __restrict__ b4, int Kx)
{
    const int K = Kx + 1024;
    const int tpr = K >> 2;
    const int idx = blockIdx.x * 256 + threadIdx.x;
    const int np = idx / tpr;
    const int k4 = (idx - np * tpr) * 4;
    const int c = ((np >> 6) << 4) + (np & 15);
    const int g = (np >> 4) & 3;
    const int srow = (g == 0 ? c : (g == 1 ? 1024 + c : 2048 + c));
    float4 v = make_float4(0.f, 0.f, 0.f, 0.f);
    if (k4 < Kx) {
        if (g != 3) v = *(const float4*)(Wih + (size_t)srow * Kx + k4);
    } else {
        if (g != 2) v = *(const float4*)(Whh + (size_t)srow * 1024 + (k4 - Kx));
    }
    bf16_t* dst = W4 + (size_t)np * K + k4;
    dst[0] = (bf16_t)v.x; dst[1] = (bf16_t)v.y;
    dst[2] = (bf16_t)v.z; dst[3] = (bf16_t)v.w;
    if (k4 == 0) {
        b4[np] = (g == 0) ? bih[c] + bhh[c]
               : (g == 1) ? bih[1024 + c] + bhh[1024 + c]
               : (g == 2) ? bih[2048 + c] : bhh[2048 + c];
    }
}

__global__ __launch_bounds__(256) void conv_bf16(
    const float* __restrict__ src, bf16_t* __restrict__ dst)
{
    const int i4 = (blockIdx.x * 256 + threadIdx.x) * 4;
    float4 v = *(const float4*)(src + i4);
    dst[i4 + 0] = (bf16_t)v.x; dst[i4 + 1] = (bf16_t)v.y;
    dst[i4 + 2] = (bf16_t)v.z; dst[i4 + 3] = (bf16_t)v.w;
}

__global__ __launch_bounds__(256) void init_state(
    const float* __restrict__ hidden, float* __restrict__ h0f,
    float* __restrict__ h1f, bf16_t* __restrict__ A0_0, bf16_t* __restrict__ A1_0)
{
    const int i = blockIdx.x * 256 + threadIdx.x;   // over 262144
    const int m = i >> 10, c = i & 1023;
    const float h0 = hidden[i], h1 = hidden[262144 + i];
    h0f[i] = h0; h1f[i] = h1;
    A0_0[(size_t)m * 1280 + 256 + c] = (bf16_t)h0;
    A1_0[(size_t)m * 2048 + 1024 + c] = (bf16_t)h1;
    if (c < 256) A0_0[(size_t)m * 1280 + c] = (bf16_t)0.f;
}

// ---------------------------------------------------------------------------
// LayerNorm (biased var, eps=1e-5) + exact GELU, bf16 out. One row per block.
// ---------------------------------------------------------------------------
__device__ __forceinline__ float block_reduce_sum(float v, float* red)
{
#pragma unroll
    for (int o = 32; o > 0; o >>= 1) v += __shfl_xor(v, o, 64);
    const int wid = threadIdx.x >> 6;
    if ((threadIdx.x & 63) == 0) red[wid] = v;
    __syncthreads();
    float s = red[0] + red[1] + red[2] + red[3];
    __syncthreads();
    return s;
}

template <int N>
__global__ __launch_bounds__(256) void ln_gelu(
    const float* __restrict__ X, const float* __restrict__ g,
    const float* __restrict__ b, bf16_t* __restrict__ Y)
{
    __shared__ float red[4];
    const int row = blockIdx.x;
    const int tid = threadIdx.x;
    constexpr int PT = N / 256;
    float v[PT];
    float s = 0.f;
#pragma unroll
    for (int i = 0; i < PT; i++) {
        v[i] = X[(size_t)row * N + tid + i * 256];
        s += v[i];
    }
    const float mu = block_reduce_sum(s, red) * (1.f / N);
    float s2 = 0.f;
#pragma unroll
    for (int i = 0; i < PT; i++) { float d = v[i] - mu; s2 += d * d; }
    const float var = block_reduce_sum(s2, red) * (1.f / N);
    const float inv = rsqrtf(var + 1e-5f);
#pragma unroll
    for (int i = 0; i < PT; i++) {
        const int c = tid + i * 256;
        const float t = (v[i] - mu) * inv * g[c] + b[c];
        Y[(size_t)row * N + c] = (bf16_t)(0.5f * t * (1.f + erff(t * 0.70710678118654752f)));
    }
}

// ---------------------------------------------------------------------------
// Fused LN2+GELU -> fc3 (K=512, N=256, bf16) -> softmax. Block = 4 rows
// (1 wave/row). Wave reads its raw fc2 row (fp32), LN+GELU in registers via
// shuffle reduce, stages bf16 row in LDS, then GEMV + softmax.
// Writes dout[b,t,:] fp32 + bf16 feedback into A0w.
// ---------------------------------------------------------------------------
__global__ __launch_bounds__(256) void fc3_ln_softmax(
    const float* __restrict__ X, const float* __restrict__ lng,
    const float* __restrict__ lnb, const bf16_t* __restrict__ W,
    const float* __restrict__ bias, float* __restrict__ dout,
    bf16_t* __restrict__ a0w, int t)
{
    __shared__ __align__(16) bf16_t arow[4][512];
    const int wv = threadIdx.x >> 6, lane = threadIdx.x & 63;
    const int row = blockIdx.x * 4 + wv;

    // ---- LN2 + GELU on this wave's row ----
    float v[8];
    float s = 0.f;
#pragma unroll
    for (int i = 0; i < 8; i++) {
        v[i] = X[(size_t)row * 512 + lane + 64 * i];
        s += v[i];
    }
#pragma unroll
    for (int o = 32; o > 0; o >>= 1) s += __shfl_xor(s, o, 64);
    const float mu = s * (1.f / 512.f);
    float s2 = 0.f;
#pragma unroll
    for (int i = 0; i < 8; i++) { float d = v[i] - mu; s2 += d * d; }
#pragma unroll
    for (int o = 32; o > 0; o >>= 1) s2 += __shfl_xor(s2, o, 64);
    const float inv = rsqrtf(s2 * (1.f / 512.f) + 1e-5f);
#pragma unroll
    for (int i = 0; i < 8; i++) {
        const int c = lane + 64 * i;
        const float tt = (v[i] - mu) * inv * lng[c] + lnb[c];
        arow[wv][c] = (bf16_t)(0.5f * tt * (1.f + erff(tt * 0.70710678118654752f)));
    }
    // wave-private LDS row: no block barrier needed (in-wave ordering)

    // ---- fc3 GEMV: lane l owns cols {l, l+64, l+128, l+192} ----
    float acc[4];
#pragma unroll
    for (int j = 0; j < 4; j++) acc[j] = bias[lane + 64 * j];
    for (int k = 0; k < 512; k += 8) {
        bf16x8 a8 = *(const bf16x8*)(&arow[wv][k]);   // wave-uniform broadcast
#pragma unroll
        for (int j = 0; j < 4; j++) {
            bf16x8 w8 = *(const bf16x8*)(W + (size_t)(lane + 64 * j) * 512 + k);
            float ss = 0.f;
#pragma unroll
            for (int e = 0; e < 8; e++) ss += (float)a8[e] * (float)w8[e];
            acc[j] += ss;
        }
    }
    // ---- softmax ----
    float mx = fmaxf(fmaxf(acc[0], acc[1]), fmaxf(acc[2], acc[3]));
#pragma unroll
    for (int o = 32; o > 0; o >>= 1) mx = fmaxf(mx, __shfl_xor(mx, o, 64));
    float e[4], es = 0.f;
#pragma unroll
    for (int j = 0; j < 4; j++) { e[j] = expf(acc[j] - mx); es += e[j]; }
#pragma unroll
    for (int o = 32; o > 0; o >>= 1) es += __shfl_xor(es, o, 64);
    const float isum = 1.f / es;
#pragma unroll
    for (int j = 0; j < 4; j++) {
        const float pv = e[j] * isum;
        const int c = lane + 64 * j;
        dout[((size_t)row * 64 + t) * 256 + c] = pv;
        a0w[(size_t)row * 1280 + c] = (bf16_t)pv;
    }
}

extern "C" void kernel_launch(void* const* d_in, const int* in_sizes, int n_in,
                              void* d_out, int out_size, void* d_ws, size_t ws_size,
                              hipStream_t stream)
{
    const float* hidden = (const float*)d_in[0];
    const float* W_ih0  = (const float*)d_in[1];
    const float* W_hh0  = (const float*)d_in[2];
    const float* b_ih0  = (const float*)d_in[3];
    const float* b_hh0  = (const float*)d_in[4];
    const float* W_ih1  = (const float*)d_in[5];
    const float* W_hh1  = (const float*)d_in[6];
    const float* b_ih1  = (const float*)d_in[7];
    const float* b_hh1  = (const float*)d_in[8];
    const float* fc1_w  = (const float*)d_in[9];
    const float* fc1_b  = (const float*)d_in[10];
    const float* ln1_g  = (const float*)d_in[11];
    const float* ln1_b  = (const float*)d_in[12];
    const float* fc2_w  = (const float*)d_in[13];
    const float* fc2_b  = (const float*)d_in[14];
    const float* ln2_g  = (const float*)d_in[15];
    const float* ln2_b  = (const float*)d_in[16];
    const float* fc3_w  = (const float*)d_in[17];
    const float* fc3_b  = (const float*)d_in[18];
    float* dout = (float*)d_out;

    char* p = (char*)d_ws;
    auto alloc = [&](size_t bytes) { void* r = (void*)p; p += (bytes + 255) & ~(size_t)255; return r; };
    float*  h0f   = (float*)alloc(262144 * 4);
    float*  h1f   = (float*)alloc(262144 * 4);
    bf16_t* A0[2] = { (bf16_t*)alloc(256 * 1280 * 2), (bf16_t*)alloc(256 * 1280 * 2) };
    bf16_t* A1[2] = { (bf16_t*)alloc(256 * 2048 * 2), (bf16_t*)alloc(256 * 2048 * 2) };
    bf16_t* h1b   = (bf16_t*)alloc(262144 * 2);
    float*  a1r   = (float*)alloc(262144 * 4);
    bf16_t* a1b   = (bf16_t*)alloc(262144 * 2);
    float*  a2r   = (float*)alloc(131072 * 4);
    float*  b4_0  = (float*)alloc(4096 * 4);
    float*  b4_1  = (float*)alloc(4096 * 4);
    bf16_t* W4_0  = (bf16_t*)alloc((size_t)4096 * 1280 * 2);
    bf16_t* W4_1  = (bf16_t*)alloc((size_t)4096 * 2048 * 2);
    bf16_t* fc1wb = (bf16_t*)alloc((size_t)1048576 * 2);
    bf16_t* fc2wb = (bf16_t*)alloc((size_t)524288 * 2);
    bf16_t* fc3wb = (bf16_t*)alloc((size_t)131072 * 2);

    // weight prep (graph-safe, every call)
    build_w4<<<5120, 256, 0, stream>>>(W_ih0, W_hh0, b_ih0, b_hh0, W4_0, b4_0, 256);
    build_w4<<<8192, 256, 0, stream>>>(W_ih1, W_hh1, b_ih1, b_hh1, W4_1, b4_1, 1024);
    conv_bf16<<<1024, 256, 0, stream>>>(fc1_w, fc1wb);
    conv_bf16<<<512, 256, 0, stream>>>(fc2_w, fc2wb);
    conv_bf16<<<128, 256, 0, stream>>>(fc3_w, fc3wb);
    init_state<<<1024, 256, 0, stream>>>(hidden, h0f, h1f, A0[0], A1[0]);

    for (int t = 0; t < 64; t++) {
        bf16_t* A0r = A0[t & 1];
        bf16_t* A0w = A0[(t + 1) & 1];
        bf16_t* A1r = A1[t & 1];
        bf16_t* A1w = A1[(t + 1) & 1];

        // GRU layer 0: reads A0r=[out|h0]; updates h0f; writes bf16 h0 into
        // A1r[:, :1024] (gru1, this step) and A0w[:, 256:1280] (next step).
        gemm_v4<1><<<dim3(64, 8), 128, 0, stream>>>(
            A0r, W4_0, b4_0, 1280, nullptr, 0,
            h0f, A1r, 2048, 0, A0w, 1280, 256);
        // GRU layer 1: reads A1r=[h0_new|h1_old]; updates h1f; writes bf16 h1
        // into A1w[:, 1024:] (next step) and h1b (fc1 input).
        gemm_v4<1><<<dim3(64, 8), 128, 0, stream>>>(
            A1r, W4_1, b4_1, 2048, nullptr, 0,
            h1f, A1w, 2048, 1024, h1b, 1024, 0);
        // FC head
        gemm_v4<0><<<dim3(16, 8), 128, 0, stream>>>(
            h1b, fc1wb, fc1_b, 1024, a1r, 1024, nullptr, nullptr, 0, 0, nullptr, 0, 0);
        ln_gelu<1024><<<256, 256, 0, stream>>>(a1r, ln1_g, ln1_b, a1b);
        gemm_v4<0><<<dim3(8, 8), 128, 0, stream>>>(
            a1b, fc2wb, fc2_b, 1024, a2r, 512, nullptr, nullptr, 0, 0, nullptr, 0, 0);
        fc3_ln_softmax<<<64, 256, 0, stream>>>(
            a2r, ln2_g, ln2_b, fc3wb, fc3_b, dout, A0w, t);
    }
}